// Round 1
// baseline (830.622 us; speedup 1.0000x reference)
//
#include <hip/hip_runtime.h>
#include <math.h>

#define EPSV 1e-5f

// ---------------- setup kernels ----------------

__global__ void k_deg(const int* __restrict__ dst, int E, int* __restrict__ deg) {
    int e = blockIdx.x * 256 + threadIdx.x;
    if (e < E) atomicAdd(&deg[dst[e]], 1);
}

// single-block exclusive scan over N ints -> offs[0..N]
__global__ void k_scan(const int* __restrict__ deg, int N, int* __restrict__ offs) {
    __shared__ int buf[1024];
    int t = threadIdx.x;
    int carry = 0;
    for (int base = 0; base < N; base += 1024) {
        int v = (base + t < N) ? deg[base + t] : 0;
        buf[t] = v;
        __syncthreads();
        for (int off = 1; off < 1024; off <<= 1) {
            int x = (t >= off) ? buf[t - off] : 0;
            __syncthreads();
            buf[t] += x;
            __syncthreads();
        }
        if (base + t < N) offs[base + t] = carry + buf[t] - v;
        int total = buf[1023];
        __syncthreads();
        carry += total;
    }
    if (t == 0) offs[N] = carry;
}

__global__ void k_logsum(const int* __restrict__ deg, int N, float* __restrict__ lsum) {
    __shared__ float red[256];
    int i = blockIdx.x * 256 + threadIdx.x;
    float v = 0.f;
    if (i < N) {
        float dc = fmaxf((float)deg[i], 1.f);
        v = logf(dc + 1.f);
    }
    red[threadIdx.x] = v;
    __syncthreads();
    for (int s = 128; s > 0; s >>= 1) {
        if (threadIdx.x < s) red[threadIdx.x] += red[threadIdx.x + s];
        __syncthreads();
    }
    if (threadIdx.x == 0) atomicAdd(lsum, red[0]);
}

__global__ void k_scalers(const int* __restrict__ deg, int N, const float* __restrict__ lsum,
                          float* __restrict__ amp, float* __restrict__ att) {
    int i = blockIdx.x * 256 + threadIdx.x;
    if (i >= N) return;
    float dc = fmaxf((float)deg[i], 1.f);
    float ld = logf(dc + 1.f);
    float avg = *lsum / (float)N;
    amp[i] = ld / avg;
    att[i] = avg / ld;
}

__global__ void k_scatter(const int* __restrict__ src, const int* __restrict__ dst, int E,
                          const int* __restrict__ offs, int* __restrict__ cursor,
                          int* __restrict__ srcSorted) {
    int e = blockIdx.x * 256 + threadIdx.x;
    if (e >= E) return;
    int d = dst[e];
    int pos = offs[d] + atomicAdd(&cursor[d], 1);
    srcSorted[pos] = src[e];
}

// Wfull[l][k][j] for k in [0,320), j in [0,192): folded post_w @ lin_w with
// layout: k<64 -> h rows (only third 0 nonzero); k>=64 -> agg rows, third = j/64
__global__ void k_fold(const float* __restrict__ post_w, const float* __restrict__ lin_w,
                       float* __restrict__ Wfull) {
    int l = blockIdx.y;
    int k = blockIdx.x;      // 0..319
    int j = threadIdx.x;     // 0..191
    int third = j >> 6, c = j & 63;
    float out = 0.f;
    int r = -1;
    if (k < 64) r = (third == 0) ? k : -1;
    else        r = 64 + third * 256 + (k - 64);
    if (r >= 0) {
        const float* pw = post_w + (size_t)(l * 832 + r) * 64;
        const float* lw = lin_w + (size_t)l * 64 * 64;
        float s = 0.f;
        for (int kk = 0; kk < 64; ++kk) s += pw[kk] * lw[kk * 64 + c];
        out = s;
    }
    Wfull[((size_t)l * 320 + k) * 192 + j] = out;
}

__global__ void k_foldb(const float* __restrict__ post_b, const float* __restrict__ lin_b,
                        const float* __restrict__ lin_w, float* __restrict__ bpp) {
    int l = blockIdx.x;
    int c = threadIdx.x;
    const float* pb = post_b + l * 64;
    const float* lw = lin_w + (size_t)l * 64 * 64;
    float s = lin_b[l * 64 + c];
    for (int k = 0; k < 64; ++k) s += pb[k] * lw[k * 64 + c];
    bpp[l * 64 + c] = s;
}

// ---------------- per-layer kernels ----------------

// PQ[M,128] = h[M,64] @ [Wt | Ws] (+ pre_b on first 64 cols)
// Wt = pre_w rows 0:64, Ws = pre_w rows 64:128 (each [64,64])
__global__ __launch_bounds__(256) void k_gemm1(const float* __restrict__ h,
                                               const float* __restrict__ pre_w,
                                               const float* __restrict__ pre_b,
                                               float* __restrict__ PQ, int M) {
    __shared__ float hT[64][68];   // [k][r]
    __shared__ float Wc[64][132];  // [k][c]
    int t = threadIdx.x;
    int rows0 = blockIdx.x * 64;
    // load h tile transposed
    {
        int r = t >> 2, k0 = (t & 3) * 16;
        int row = rows0 + r;
#pragma unroll
        for (int j = 0; j < 4; ++j) {
            float4 v = make_float4(0.f, 0.f, 0.f, 0.f);
            if (row < M) v = *(const float4*)&h[(size_t)row * 64 + k0 + 4 * j];
            hT[k0 + 4 * j + 0][r] = v.x;
            hT[k0 + 4 * j + 1][r] = v.y;
            hT[k0 + 4 * j + 2][r] = v.z;
            hT[k0 + 4 * j + 3][r] = v.w;
        }
    }
    // load combined weight [k=64][c=128]
#pragma unroll
    for (int jj = 0; jj < 8; ++jj) {
        int f = jj * 1024 + t * 4;
        int k = f >> 7, c = f & 127;
        const float* src = (c < 64) ? &pre_w[k * 64 + c] : &pre_w[(64 + k) * 64 + (c - 64)];
        *(float4*)&Wc[k][c] = *(const float4*)src;
    }
    __syncthreads();

    int r0 = (t >> 4) * 4, c0 = (t & 15) * 8;
    float acc[4][8];
#pragma unroll
    for (int r = 0; r < 4; ++r)
#pragma unroll
        for (int j = 0; j < 8; ++j) acc[r][j] = 0.f;

#pragma unroll 4
    for (int k = 0; k < 64; ++k) {
        float4 a = *(float4*)&hT[k][r0];
        float4 b0 = *(float4*)&Wc[k][c0];
        float4 b1 = *(float4*)&Wc[k][c0 + 4];
        float av[4] = {a.x, a.y, a.z, a.w};
        float bv[8] = {b0.x, b0.y, b0.z, b0.w, b1.x, b1.y, b1.z, b1.w};
#pragma unroll
        for (int r = 0; r < 4; ++r)
#pragma unroll
            for (int j = 0; j < 8; ++j) acc[r][j] = fmaf(av[r], bv[j], acc[r][j]);
    }

    float bias[8];
#pragma unroll
    for (int j = 0; j < 8; ++j) bias[j] = (c0 < 64) ? pre_b[c0 + j] : 0.f;
#pragma unroll
    for (int r = 0; r < 4; ++r) {
        int row = rows0 + r0 + r;
        if (row >= M) continue;
        float4 o0 = make_float4(acc[r][0] + bias[0], acc[r][1] + bias[1],
                                acc[r][2] + bias[2], acc[r][3] + bias[3]);
        float4 o1 = make_float4(acc[r][4] + bias[4], acc[r][5] + bias[5],
                                acc[r][6] + bias[6], acc[r][7] + bias[7]);
        *(float4*)&PQ[(size_t)row * 128 + c0] = o0;
        *(float4*)&PQ[(size_t)row * 128 + c0 + 4] = o1;
    }
}

// one wave (64 lanes) per node; lane = feature
__global__ __launch_bounds__(256) void k_agg(const float* __restrict__ PQ,
                                             const int* __restrict__ offs,
                                             const int* __restrict__ srcSorted,
                                             float* __restrict__ AGG, int N) {
    int idx = blockIdx.x * 4 + (threadIdx.x >> 6);
    int lane = threadIdx.x & 63;
    if (idx >= N) return;
    int beg = offs[idx], end = offs[idx + 1];
    float p = PQ[(size_t)idx * 128 + lane];
    float sum = 0.f, sq = 0.f;
    float mx = -3.4e38f, mn = 3.4e38f;
    for (int e = beg; e < end; ++e) {
        int s = srcSorted[e];
        float q = PQ[(size_t)s * 128 + 64 + lane];
        float m = p + q;
        sum += m;
        sq = fmaf(m, m, sq);
        mx = fmaxf(mx, m);
        mn = fminf(mn, m);
    }
    int deg = end - beg;
    float dc = fmaxf((float)deg, 1.f);
    float mean = sum / dc;
    float var = fmaxf(sq / dc - mean * mean, 0.f);
    float sd = sqrtf(var + EPSV);
    if (deg == 0) { mx = 0.f; mn = 0.f; }
    size_t o = (size_t)idx * 256;
    AGG[o + lane] = mean;
    AGG[o + 64 + lane] = mx;
    AGG[o + 128 + lane] = mn;
    AGG[o + 192 + lane] = sd;
}

// hOut[M,64] = hIn + hIn@W'_h + agg@W'_1 + amp*(agg@W'_2) + att*(agg@W'_3) + b'
// via Wfull[320,192] (k<64: h part, only cols 0:64 nonzero; k>=64: agg part)
__global__ __launch_bounds__(256) void k_gemm2(const float* __restrict__ hIn,
                                               const float* __restrict__ AGG,
                                               const float* __restrict__ Wfull,
                                               const float* __restrict__ bpp,
                                               const float* __restrict__ amp,
                                               const float* __restrict__ att,
                                               float* __restrict__ hOut, int M) {
    __shared__ float XsT[32][68];   // [k][r]
    __shared__ float Ws[32][196];   // [k][c 0..191]
    int t = threadIdx.x;
    int rows0 = blockIdx.x * 64;
    int r0 = (t >> 4) * 4, c0 = (t & 15) * 4;
    float acc[4][12];
#pragma unroll
    for (int r = 0; r < 4; ++r)
#pragma unroll
        for (int j = 0; j < 12; ++j) acc[r][j] = 0.f;

    for (int chunk = 0; chunk < 10; ++chunk) {
        int kbase = chunk * 32;
        // load X^T tile: 64 rows x 32 k
        {
            int r = t >> 2, k0 = (t & 3) * 8;
            int row = rows0 + r;
            const float* src;
            int stride;
            if (kbase < 64) { src = hIn + kbase; stride = 64; }
            else            { src = AGG + (kbase - 64); stride = 256; }
#pragma unroll
            for (int j = 0; j < 2; ++j) {
                float4 v = make_float4(0.f, 0.f, 0.f, 0.f);
                if (row < M) v = *(const float4*)&src[(size_t)row * stride + k0 + 4 * j];
                XsT[k0 + 4 * j + 0][r] = v.x;
                XsT[k0 + 4 * j + 1][r] = v.y;
                XsT[k0 + 4 * j + 2][r] = v.z;
                XsT[k0 + 4 * j + 3][r] = v.w;
            }
        }
        // load W tile: 32 k x 192 c
#pragma unroll
        for (int jj = 0; jj < 6; ++jj) {
            int f = jj * 1024 + t * 4;
            int kk = f / 192, c = f % 192;
            *(float4*)&Ws[kk][c] = *(const float4*)&Wfull[(size_t)(kbase + kk) * 192 + c];
        }
        __syncthreads();

        if (kbase < 64) {
            // h-part: only cols 0:64 of W nonzero
#pragma unroll 4
            for (int kk = 0; kk < 32; ++kk) {
                float4 a = *(float4*)&XsT[kk][r0];
                float4 b0 = *(float4*)&Ws[kk][c0];
                float av[4] = {a.x, a.y, a.z, a.w};
                float bv[4] = {b0.x, b0.y, b0.z, b0.w};
#pragma unroll
                for (int r = 0; r < 4; ++r)
#pragma unroll
                    for (int j = 0; j < 4; ++j) acc[r][j] = fmaf(av[r], bv[j], acc[r][j]);
            }
        } else {
#pragma unroll 2
            for (int kk = 0; kk < 32; ++kk) {
                float4 a = *(float4*)&XsT[kk][r0];
                float4 b0 = *(float4*)&Ws[kk][c0];
                float4 b1 = *(float4*)&Ws[kk][c0 + 64];
                float4 b2 = *(float4*)&Ws[kk][c0 + 128];
                float av[4] = {a.x, a.y, a.z, a.w};
                float bv[12] = {b0.x, b0.y, b0.z, b0.w, b1.x, b1.y, b1.z, b1.w,
                                b2.x, b2.y, b2.z, b2.w};
#pragma unroll
                for (int r = 0; r < 4; ++r)
#pragma unroll
                    for (int j = 0; j < 12; ++j) acc[r][j] = fmaf(av[r], bv[j], acc[r][j]);
            }
        }
        __syncthreads();
    }

    // epilogue: combine thirds with amp/att, add residual + folded bias
#pragma unroll
    for (int r = 0; r < 4; ++r) {
        int row = rows0 + r0 + r;
        if (row >= M) continue;
        float am = amp[row], at = att[row];
        float4 hv = *(const float4*)&hIn[(size_t)row * 64 + c0];
        float4 bb = *(const float4*)&bpp[c0];
        float4 o;
        o.x = acc[r][0] + am * acc[r][4] + at * acc[r][8] + hv.x + bb.x;
        o.y = acc[r][1] + am * acc[r][5] + at * acc[r][9] + hv.y + bb.y;
        o.z = acc[r][2] + am * acc[r][6] + at * acc[r][10] + hv.z + bb.z;
        o.w = acc[r][3] + am * acc[r][7] + at * acc[r][11] + hv.w + bb.w;
        *(float4*)&hOut[(size_t)row * 64 + c0] = o;
    }
}

// ---------------- launch ----------------

extern "C" void kernel_launch(void* const* d_in, const int* in_sizes, int n_in,
                              void* d_out, int out_size, void* d_ws, size_t ws_size,
                              hipStream_t stream) {
    const float* x      = (const float*)d_in[0];
    const int*   ei     = (const int*)d_in[1];
    const float* pre_w  = (const float*)d_in[2];
    const float* pre_b  = (const float*)d_in[3];
    const float* post_w = (const float*)d_in[4];
    const float* post_b = (const float*)d_in[5];
    const float* lin_w  = (const float*)d_in[6];
    const float* lin_b  = (const float*)d_in[7];

    const int N = in_sizes[0] / 64;
    const int E = in_sizes[1] / 2;
    const int L = in_sizes[2] / (128 * 64);

    const int* srcIdx = ei;
    const int* dstIdx = ei + E;

    char* ws = (char*)d_ws;
    size_t off = 0;
    auto alloc = [&](size_t bytes) {
        void* p = ws + off;
        off += (bytes + 255) & ~(size_t)255;
        return p;
    };
    int*   deg       = (int*)alloc((size_t)N * 4);
    int*   offs      = (int*)alloc((size_t)(N + 1) * 4);
    int*   cursor    = (int*)alloc((size_t)N * 4);
    int*   srcSorted = (int*)alloc((size_t)E * 4);
    float* amp       = (float*)alloc((size_t)N * 4);
    float* att       = (float*)alloc((size_t)N * 4);
    float* lsum      = (float*)alloc(256);
    float* Wfull     = (float*)alloc((size_t)L * 320 * 192 * 4);
    float* bpp       = (float*)alloc((size_t)L * 64 * 4);
    float* PQ        = (float*)alloc((size_t)N * 128 * 4);
    float* AGG       = (float*)alloc((size_t)N * 256 * 4);
    float* hA        = (float*)alloc((size_t)N * 64 * 4);
    float* hB        = (float*)alloc((size_t)N * 64 * 4);
    (void)ws_size;

    hipMemsetAsync(deg, 0, (size_t)N * 4, stream);
    hipMemsetAsync(cursor, 0, (size_t)N * 4, stream);
    hipMemsetAsync(lsum, 0, 4, stream);

    k_deg<<<(E + 255) / 256, 256, 0, stream>>>(dstIdx, E, deg);
    k_scan<<<1, 1024, 0, stream>>>(deg, N, offs);
    k_logsum<<<(N + 255) / 256, 256, 0, stream>>>(deg, N, lsum);
    k_scalers<<<(N + 255) / 256, 256, 0, stream>>>(deg, N, lsum, amp, att);
    k_scatter<<<(E + 255) / 256, 256, 0, stream>>>(srcIdx, dstIdx, E, offs, cursor, srcSorted);
    k_fold<<<dim3(320, L), 192, 0, stream>>>(post_w, lin_w, Wfull);
    k_foldb<<<L, 64, 0, stream>>>(post_b, lin_b, lin_w, bpp);

    const float* hIn = x;
    float* hbuf[2] = {hA, hB};
    for (int l = 0; l < L; ++l) {
        float* hOut = (l == L - 1) ? (float*)d_out : hbuf[l & 1];
        k_gemm1<<<(N + 63) / 64, 256, 0, stream>>>(hIn, pre_w + (size_t)l * 128 * 64,
                                                   pre_b + (size_t)l * 64, PQ, N);
        k_agg<<<(N + 3) / 4, 256, 0, stream>>>(PQ, offs, srcSorted, AGG, N);
        k_gemm2<<<(N + 63) / 64, 256, 0, stream>>>(hIn, AGG,
                                                   Wfull + (size_t)l * 320 * 192,
                                                   bpp + (size_t)l * 64,
                                                   amp, att, hOut, N);
        hIn = hOut;
    }
}

// Round 2
// 800.730 us; speedup vs baseline: 1.0373x; 1.0373x over previous
//
#include <hip/hip_runtime.h>
#include <math.h>

#define EPSV 1e-5f

typedef short s16x8 __attribute__((ext_vector_type(8)));
typedef float f32x4 __attribute__((ext_vector_type(4)));
typedef unsigned short u16;

#define MFMA(a, b, c) __builtin_amdgcn_mfma_f32_16x16x32_bf16(a, b, c, 0, 0, 0)

__device__ inline u16 f2bf(float f) {
    unsigned u = __float_as_uint(f);
    return (u16)((u + 0x7FFF + ((u >> 16) & 1)) >> 16);
}
__device__ inline float bf2f(u16 h) { return __uint_as_float(((unsigned)h) << 16); }

__device__ inline void split8(const float4& a, const float4& b, s16x8& hv, s16x8& lv) {
    float f[8] = {a.x, a.y, a.z, a.w, b.x, b.y, b.z, b.w};
#pragma unroll
    for (int i = 0; i < 8; ++i) {
        u16 h = f2bf(f[i]);
        hv[i] = (short)h;
        lv[i] = (short)f2bf(f[i] - bf2f(h));
    }
}

// ---------------- setup kernels ----------------

__global__ void k_deg(const int* __restrict__ dst, int E, int* __restrict__ deg) {
    int e = blockIdx.x * 256 + threadIdx.x;
    if (e < E) atomicAdd(&deg[dst[e]], 1);
}

// partial sums: each block sums 1024 degs
__global__ void k_part(const int* __restrict__ deg, int N, int* __restrict__ part) {
    __shared__ int red[256];
    int base = blockIdx.x * 1024, t = threadIdx.x;
    int s = 0;
#pragma unroll
    for (int j = 0; j < 4; ++j) {
        int i = base + j * 256 + t;
        if (i < N) s += deg[i];
    }
    red[t] = s;
    __syncthreads();
    for (int o = 128; o > 0; o >>= 1) {
        if (t < o) red[t] += red[t + o];
        __syncthreads();
    }
    if (t == 0) part[blockIdx.x] = red[0];
}

__global__ void k_scanpart(const int* __restrict__ part, int G, int E,
                           int* __restrict__ partOffs, int* __restrict__ offs, int N) {
    __shared__ int buf[1024];
    int t = threadIdx.x;
    int v = (t < G) ? part[t] : 0;
    buf[t] = v;
    __syncthreads();
    for (int o = 1; o < 1024; o <<= 1) {
        int x = (t >= o) ? buf[t - o] : 0;
        __syncthreads();
        buf[t] += x;
        __syncthreads();
    }
    if (t < G) partOffs[t] = buf[t] - v;
    if (t == 0) offs[N] = E;
}

__global__ void k_offsets(const int* __restrict__ deg, int N,
                          const int* __restrict__ partOffs, int* __restrict__ offs) {
    __shared__ int buf[1024];
    int base = blockIdx.x * 1024, t = threadIdx.x;
    int v = (base + t < N) ? deg[base + t] : 0;
    buf[t] = v;
    __syncthreads();
    for (int o = 1; o < 1024; o <<= 1) {
        int x = (t >= o) ? buf[t - o] : 0;
        __syncthreads();
        buf[t] += x;
        __syncthreads();
    }
    if (base + t < N) offs[base + t] = partOffs[blockIdx.x] + buf[t] - v;
}

__global__ void k_logsum(const int* __restrict__ deg, int N, float* __restrict__ lsum) {
    __shared__ float red[256];
    int i = blockIdx.x * 256 + threadIdx.x;
    float v = 0.f;
    if (i < N) {
        float dc = fmaxf((float)deg[i], 1.f);
        v = logf(dc + 1.f);
    }
    red[threadIdx.x] = v;
    __syncthreads();
    for (int s = 128; s > 0; s >>= 1) {
        if (threadIdx.x < s) red[threadIdx.x] += red[threadIdx.x + s];
        __syncthreads();
    }
    if (threadIdx.x == 0) atomicAdd(lsum, red[0]);
}

__global__ void k_scalers(const int* __restrict__ deg, int N, const float* __restrict__ lsum,
                          float* __restrict__ amp, float* __restrict__ att) {
    int i = blockIdx.x * 256 + threadIdx.x;
    if (i >= N) return;
    float dc = fmaxf((float)deg[i], 1.f);
    float ld = logf(dc + 1.f);
    float avg = *lsum / (float)N;
    amp[i] = ld / avg;
    att[i] = avg / ld;
}

__global__ void k_scatter(const int* __restrict__ src, const int* __restrict__ dst, int E,
                          const int* __restrict__ offs, int* __restrict__ cursor,
                          int* __restrict__ srcSorted) {
    int e = blockIdx.x * 256 + threadIdx.x;
    if (e >= E) return;
    int d = dst[e];
    int pos = offs[d] + atomicAdd(&cursor[d], 1);
    srcSorted[pos] = src[e];
}

// pre_w combined [64k x 128c], transposed to [c][k], split hi/lo bf16
__global__ void k_prew(const float* __restrict__ pre_w, u16* __restrict__ WpT_hi,
                       u16* __restrict__ WpT_lo) {
    int c = blockIdx.x, l = blockIdx.y, k = threadIdx.x;  // k<64
    float v = pre_w[(size_t)l * 8192 + (size_t)(k + (c >= 64 ? 64 : 0)) * 64 + (c & 63)];
    u16 h = f2bf(v);
    size_t o = ((size_t)l * 128 + c) * 64 + k;
    WpT_hi[o] = h;
    WpT_lo[o] = f2bf(v - bf2f(h));
}

// folded post_w @ lin_w -> WT[l][j=192][k=320] hi/lo bf16 (transposed, n-major)
// k<64: h rows (nonzero only for third 0); k>=64: agg rows, third = j/64
__global__ void k_fold(const float* __restrict__ post_w, const float* __restrict__ lin_w,
                       u16* __restrict__ WT_hi, u16* __restrict__ WT_lo) {
    int l = blockIdx.y, k = blockIdx.x, j = threadIdx.x;  // k<320, j<192
    int third = j >> 6, c = j & 63;
    float out = 0.f;
    int r = -1;
    if (k < 64) r = (third == 0) ? k : -1;
    else        r = 64 + third * 256 + (k - 64);
    if (r >= 0) {
        const float* pw = post_w + (size_t)(l * 832 + r) * 64;
        const float* lw = lin_w + (size_t)l * 64 * 64;
        float s = 0.f;
        for (int kk = 0; kk < 64; ++kk) s += pw[kk] * lw[kk * 64 + c];
        out = s;
    }
    u16 h = f2bf(out);
    size_t o = ((size_t)l * 192 + j) * 320 + k;
    WT_hi[o] = h;
    WT_lo[o] = f2bf(out - bf2f(h));
}

__global__ void k_foldb(const float* __restrict__ post_b, const float* __restrict__ lin_b,
                        const float* __restrict__ lin_w, float* __restrict__ bpp) {
    int l = blockIdx.x, c = threadIdx.x;
    const float* pb = post_b + l * 64;
    const float* lw = lin_w + (size_t)l * 64 * 64;
    float s = lin_b[l * 64 + c];
    for (int k = 0; k < 64; ++k) s += pb[k] * lw[k * 64 + c];
    bpp[l * 64 + c] = s;
}

// ---------------- per-layer kernels ----------------

// P[M,64](+bias) , Q[M,64] = h[M,64] @ [Wt | Ws] via split-bf16 MFMA
__global__ __launch_bounds__(256) void k_gemm1(const float* __restrict__ h,
                                               const u16* __restrict__ WpT_hi,
                                               const u16* __restrict__ WpT_lo,
                                               const float* __restrict__ pre_b,
                                               float* __restrict__ P, float* __restrict__ Q,
                                               int M) {
    __shared__ u16 Ah[64 * 72], Al[64 * 72];    // [row][k 0:64], pitch 72
    __shared__ u16 Bh[128 * 72], Bl[128 * 72];  // [col][k 0:64], pitch 72
    int t = threadIdx.x, wid = t >> 6, lane = t & 63;
    int rows0 = blockIdx.x * 64;
    int quad = lane >> 4, l16 = lane & 15;
    int wm = wid & 1, wn = wid >> 1;

    // stage A (split fp32 -> hi/lo): 64 rows x 8 segs
#pragma unroll
    for (int it = 0; it < 2; ++it) {
        int task = it * 256 + t;
        int r = task >> 3, seg = task & 7;
        int row = rows0 + r;
        float4 v0 = make_float4(0.f, 0.f, 0.f, 0.f), v1 = v0;
        if (row < M) {
            v0 = *(const float4*)&h[(size_t)row * 64 + seg * 8];
            v1 = *(const float4*)&h[(size_t)row * 64 + seg * 8 + 4];
        }
        s16x8 hv, lv;
        split8(v0, v1, hv, lv);
        *(s16x8*)&Ah[r * 72 + seg * 8] = hv;
        *(s16x8*)&Al[r * 72 + seg * 8] = lv;
    }
    // stage B: 128 cols x 8 segs, pre-split
#pragma unroll
    for (int it = 0; it < 4; ++it) {
        int task = it * 256 + t;
        int c = task >> 3, seg = task & 7;
        *(s16x8*)&Bh[c * 72 + seg * 8] = *(const s16x8*)&WpT_hi[(size_t)c * 64 + seg * 8];
        *(s16x8*)&Bl[c * 72 + seg * 8] = *(const s16x8*)&WpT_lo[(size_t)c * 64 + seg * 8];
    }
    __syncthreads();

    f32x4 acc[2][4];
#pragma unroll
    for (int mt = 0; mt < 2; ++mt)
#pragma unroll
        for (int tt = 0; tt < 4; ++tt) acc[mt][tt] = (f32x4){0.f, 0.f, 0.f, 0.f};

#pragma unroll
    for (int c = 0; c < 2; ++c) {
        s16x8 ah[2], al[2];
#pragma unroll
        for (int mt = 0; mt < 2; ++mt) {
            int r = wm * 32 + mt * 16 + l16;
            ah[mt] = *(s16x8*)&Ah[r * 72 + c * 32 + quad * 8];
            al[mt] = *(s16x8*)&Al[r * 72 + c * 32 + quad * 8];
        }
#pragma unroll
        for (int tt = 0; tt < 4; ++tt) {
            int cc = wn * 64 + tt * 16 + l16;
            s16x8 bh = *(s16x8*)&Bh[cc * 72 + c * 32 + quad * 8];
            s16x8 bl = *(s16x8*)&Bl[cc * 72 + c * 32 + quad * 8];
#pragma unroll
            for (int mt = 0; mt < 2; ++mt) {
                acc[mt][tt] = MFMA(ah[mt], bh, acc[mt][tt]);
                acc[mt][tt] = MFMA(al[mt], bh, acc[mt][tt]);
                acc[mt][tt] = MFMA(ah[mt], bl, acc[mt][tt]);
            }
        }
    }

#pragma unroll
    for (int mt = 0; mt < 2; ++mt)
#pragma unroll
        for (int tt = 0; tt < 4; ++tt) {
            int col = wn * 64 + tt * 16 + l16;
#pragma unroll
            for (int r = 0; r < 4; ++r) {
                int row = rows0 + wm * 32 + mt * 16 + quad * 4 + r;
                if (row >= M) continue;
                float v = acc[mt][tt][r];
                if (col < 64) P[(size_t)row * 64 + col] = v + pre_b[col];
                else          Q[(size_t)row * 64 + col - 64] = v;
            }
        }
}

// one wave per node; lane = feature
__global__ __launch_bounds__(256) void k_agg(const float* __restrict__ P,
                                             const float* __restrict__ Q,
                                             const int* __restrict__ offs,
                                             const int* __restrict__ ss,
                                             float* __restrict__ AGG, int N) {
    int idx = blockIdx.x * 4 + (threadIdx.x >> 6);
    int lane = threadIdx.x & 63;
    if (idx >= N) return;
    int beg = offs[idx], end = offs[idx + 1];
    float p = P[(size_t)idx * 64 + lane];
    float sum = 0.f, sq = 0.f, mx = -3.4e38f, mn = 3.4e38f;
    int e = beg;
    for (; e + 4 <= end; e += 4) {
        int s0 = ss[e], s1 = ss[e + 1], s2 = ss[e + 2], s3 = ss[e + 3];
        float q0 = Q[(size_t)s0 * 64 + lane];
        float q1 = Q[(size_t)s1 * 64 + lane];
        float q2 = Q[(size_t)s2 * 64 + lane];
        float q3 = Q[(size_t)s3 * 64 + lane];
        float m0 = p + q0, m1 = p + q1, m2 = p + q2, m3 = p + q3;
        sum += m0; sq = fmaf(m0, m0, sq); mx = fmaxf(mx, m0); mn = fminf(mn, m0);
        sum += m1; sq = fmaf(m1, m1, sq); mx = fmaxf(mx, m1); mn = fminf(mn, m1);
        sum += m2; sq = fmaf(m2, m2, sq); mx = fmaxf(mx, m2); mn = fminf(mn, m2);
        sum += m3; sq = fmaf(m3, m3, sq); mx = fmaxf(mx, m3); mn = fminf(mn, m3);
    }
    for (; e < end; ++e) {
        int s = ss[e];
        float m = p + Q[(size_t)s * 64 + lane];
        sum += m; sq = fmaf(m, m, sq); mx = fmaxf(mx, m); mn = fminf(mn, m);
    }
    int deg = end - beg;
    float dc = fmaxf((float)deg, 1.f);
    float mean = sum / dc;
    float var = fmaxf(sq / dc - mean * mean, 0.f);
    float sd = sqrtf(var + EPSV);
    if (deg == 0) { mx = 0.f; mn = 0.f; }
    size_t o = (size_t)idx * 256;
    AGG[o + lane] = mean;
    AGG[o + 64 + lane] = mx;
    AGG[o + 128 + lane] = mn;
    AGG[o + 192 + lane] = sd;
}

// hOut = hIn + [hIn|AGG] @ WT (192 cols = 3 thirds) combined with amp/att + bpp
__global__ __launch_bounds__(256) void k_gemm2(const float* __restrict__ hIn,
                                               const float* __restrict__ AGG,
                                               const u16* __restrict__ WT_hi,
                                               const u16* __restrict__ WT_lo,
                                               const float* __restrict__ bpp,
                                               const float* __restrict__ amp,
                                               const float* __restrict__ att,
                                               float* __restrict__ hOut, int M) {
    __shared__ u16 Ah[64 * 40], Al[64 * 40];    // [row][k-chunk 32], pitch 40
    __shared__ u16 Bh[192 * 40], Bl[192 * 40];  // [col][k-chunk 32], pitch 40
    int t = threadIdx.x, wid = t >> 6, lane = t & 63;
    int rows0 = blockIdx.x * 64;
    int quad = lane >> 4, l16 = lane & 15;
    int wm = wid & 1, wn = wid >> 1;

    f32x4 acc[2][6];  // [mt][cg + third*2]
#pragma unroll
    for (int mt = 0; mt < 2; ++mt)
#pragma unroll
        for (int tt = 0; tt < 6; ++tt) acc[mt][tt] = (f32x4){0.f, 0.f, 0.f, 0.f};

    for (int chunk = 0; chunk < 10; ++chunk) {
        const float* srcF;
        int pitch, k0loc;
        if (chunk < 2) { srcF = hIn; pitch = 64; k0loc = chunk * 32; }
        else           { srcF = AGG; pitch = 256; k0loc = (chunk - 2) * 32; }
        // stage A with on-the-fly split: 64 rows x 4 segs = 256 tasks
        {
            int r = t >> 2, seg = t & 3;
            int row = rows0 + r;
            float4 v0 = make_float4(0.f, 0.f, 0.f, 0.f), v1 = v0;
            if (row < M) {
                v0 = *(const float4*)&srcF[(size_t)row * pitch + k0loc + seg * 8];
                v1 = *(const float4*)&srcF[(size_t)row * pitch + k0loc + seg * 8 + 4];
            }
            s16x8 hv, lv;
            split8(v0, v1, hv, lv);
            *(s16x8*)&Ah[r * 40 + seg * 8] = hv;
            *(s16x8*)&Al[r * 40 + seg * 8] = lv;
        }
        // stage B: (chunk<2: only cols 0:64 needed) x 4 segs
        int k0g = chunk * 32;
        int ntasks = ((chunk < 2) ? 64 : 192) * 4;
#pragma unroll
        for (int it = 0; it < 3; ++it) {
            int task = it * 256 + t;
            if (task < ntasks) {
                int c = task >> 2, seg = task & 3;
                *(s16x8*)&Bh[c * 40 + seg * 8] = *(const s16x8*)&WT_hi[(size_t)c * 320 + k0g + seg * 8];
                *(s16x8*)&Bl[c * 40 + seg * 8] = *(const s16x8*)&WT_lo[(size_t)c * 320 + k0g + seg * 8];
            }
        }
        __syncthreads();

        s16x8 ah[2], al[2];
#pragma unroll
        for (int mt = 0; mt < 2; ++mt) {
            int r = wm * 32 + mt * 16 + l16;
            ah[mt] = *(s16x8*)&Ah[r * 40 + quad * 8];
            al[mt] = *(s16x8*)&Al[r * 40 + quad * 8];
        }
        int ttmax = (chunk < 2) ? 2 : 6;
        for (int tt = 0; tt < ttmax; ++tt) {
            int cc = wn * 32 + (tt & 1) * 16 + (tt >> 1) * 64 + l16;
            s16x8 bh = *(s16x8*)&Bh[cc * 40 + quad * 8];
            s16x8 bl = *(s16x8*)&Bl[cc * 40 + quad * 8];
#pragma unroll
            for (int mt = 0; mt < 2; ++mt) {
                acc[mt][tt] = MFMA(ah[mt], bh, acc[mt][tt]);
                acc[mt][tt] = MFMA(al[mt], bh, acc[mt][tt]);
                acc[mt][tt] = MFMA(ah[mt], bl, acc[mt][tt]);
            }
        }
        __syncthreads();
    }

    // epilogue: combine thirds with amp/att, residual + folded bias
#pragma unroll
    for (int mt = 0; mt < 2; ++mt)
#pragma unroll
        for (int cg = 0; cg < 2; ++cg) {
            int col = wn * 32 + cg * 16 + l16;
            float bb = bpp[col];
#pragma unroll
            for (int r = 0; r < 4; ++r) {
                int row = rows0 + wm * 32 + mt * 16 + quad * 4 + r;
                if (row >= M) continue;
                float am = amp[row], at = att[row];
                float v = acc[mt][cg][r] + am * acc[mt][cg + 2][r] + at * acc[mt][cg + 4][r]
                        + hIn[(size_t)row * 64 + col] + bb;
                hOut[(size_t)row * 64 + col] = v;
            }
        }
}

// ---------------- launch ----------------

extern "C" void kernel_launch(void* const* d_in, const int* in_sizes, int n_in,
                              void* d_out, int out_size, void* d_ws, size_t ws_size,
                              hipStream_t stream) {
    const float* x      = (const float*)d_in[0];
    const int*   ei     = (const int*)d_in[1];
    const float* pre_w  = (const float*)d_in[2];
    const float* pre_b  = (const float*)d_in[3];
    const float* post_w = (const float*)d_in[4];
    const float* post_b = (const float*)d_in[5];
    const float* lin_w  = (const float*)d_in[6];
    const float* lin_b  = (const float*)d_in[7];

    const int N = in_sizes[0] / 64;
    const int E = in_sizes[1] / 2;
    const int L = in_sizes[2] / (128 * 64);

    const int* srcIdx = ei;
    const int* dstIdx = ei + E;

    char* ws = (char*)d_ws;
    size_t off = 0;
    auto alloc = [&](size_t bytes) {
        void* p = ws + off;
        off += (bytes + 255) & ~(size_t)255;
        return p;
    };
    int*   deg       = (int*)alloc((size_t)N * 4);
    int*   offs      = (int*)alloc((size_t)(N + 1) * 4);
    int*   cursor    = (int*)alloc((size_t)N * 4);
    int*   srcSorted = (int*)alloc((size_t)E * 4);
    int*   part      = (int*)alloc(1024 * 4);
    int*   partOffs  = (int*)alloc(1024 * 4);
    float* amp       = (float*)alloc((size_t)N * 4);
    float* att       = (float*)alloc((size_t)N * 4);
    float* lsum      = (float*)alloc(256);
    u16*   WpT_hi    = (u16*)alloc((size_t)L * 128 * 64 * 2);
    u16*   WpT_lo    = (u16*)alloc((size_t)L * 128 * 64 * 2);
    u16*   WT_hi     = (u16*)alloc((size_t)L * 192 * 320 * 2);
    u16*   WT_lo     = (u16*)alloc((size_t)L * 192 * 320 * 2);
    float* bpp       = (float*)alloc((size_t)L * 64 * 4);
    float* P         = (float*)alloc((size_t)N * 64 * 4);
    float* Q         = (float*)alloc((size_t)N * 64 * 4);
    float* AGG       = (float*)alloc((size_t)N * 256 * 4);
    float* hA        = (float*)alloc((size_t)N * 64 * 4);
    float* hB        = (float*)alloc((size_t)N * 64 * 4);
    (void)ws_size;

    hipMemsetAsync(deg, 0, (size_t)N * 4, stream);
    hipMemsetAsync(cursor, 0, (size_t)N * 4, stream);
    hipMemsetAsync(lsum, 0, 4, stream);

    int G1 = (N + 1023) / 1024;
    k_deg<<<(E + 255) / 256, 256, 0, stream>>>(dstIdx, E, deg);
    k_part<<<G1, 256, 0, stream>>>(deg, N, part);
    k_scanpart<<<1, 1024, 0, stream>>>(part, G1, E, partOffs, offs, N);
    k_offsets<<<G1, 1024, 0, stream>>>(deg, N, partOffs, offs);
    k_logsum<<<(N + 255) / 256, 256, 0, stream>>>(deg, N, lsum);
    k_scalers<<<(N + 255) / 256, 256, 0, stream>>>(deg, N, lsum, amp, att);
    k_scatter<<<(E + 255) / 256, 256, 0, stream>>>(srcIdx, dstIdx, E, offs, cursor, srcSorted);
    k_prew<<<dim3(128, L), 64, 0, stream>>>(pre_w, WpT_hi, WpT_lo);
    k_fold<<<dim3(320, L), 192, 0, stream>>>(post_w, lin_w, WT_hi, WT_lo);
    k_foldb<<<L, 64, 0, stream>>>(post_b, lin_b, lin_w, bpp);

    const float* hIn = x;
    float* hbuf[2] = {hA, hB};
    int gblk = (N + 63) / 64;
    for (int l = 0; l < L; ++l) {
        float* hOut = (l == L - 1) ? (float*)d_out : hbuf[l & 1];
        k_gemm1<<<gblk, 256, 0, stream>>>(hIn, WpT_hi + (size_t)l * 128 * 64,
                                          WpT_lo + (size_t)l * 128 * 64,
                                          pre_b + (size_t)l * 64, P, Q, N);
        k_agg<<<(N + 3) / 4, 256, 0, stream>>>(P, Q, offs, srcSorted, AGG, N);
        k_gemm2<<<gblk, 256, 0, stream>>>(hIn, AGG,
                                          WT_hi + (size_t)l * 192 * 320,
                                          WT_lo + (size_t)l * 192 * 320,
                                          bpp + (size_t)l * 64,
                                          amp, att, hOut, N);
        hIn = hOut;
    }
}

// Round 3
// 446.086 us; speedup vs baseline: 1.8620x; 1.7950x over previous
//
#include <hip/hip_runtime.h>
#include <math.h>

#define EPSV 1e-5f

typedef short s16x8 __attribute__((ext_vector_type(8)));
typedef float f32x4 __attribute__((ext_vector_type(4)));
typedef unsigned short u16;

#define MFMA(a, b, c) __builtin_amdgcn_mfma_f32_16x16x32_bf16(a, b, c, 0, 0, 0)

__device__ inline u16 f2bf(float f) {
    unsigned u = __float_as_uint(f);
    return (u16)((u + 0x7FFF + ((u >> 16) & 1)) >> 16);
}
__device__ inline float bf2f(u16 h) { return __uint_as_float(((unsigned)h) << 16); }

__device__ inline void split8(const float4& a, const float4& b, s16x8& hv, s16x8& lv) {
    float f[8] = {a.x, a.y, a.z, a.w, b.x, b.y, b.z, b.w};
#pragma unroll
    for (int i = 0; i < 8; ++i) {
        u16 h = f2bf(f[i]);
        hv[i] = (short)h;
        lv[i] = (short)f2bf(f[i] - bf2f(h));
    }
}

// ---------------- setup kernels ----------------

__global__ void k_deg(const int* __restrict__ dst, int E, int* __restrict__ deg) {
    int e = blockIdx.x * 256 + threadIdx.x;
    if (e < E) atomicAdd(&deg[dst[e]], 1);
}

__global__ void k_part(const int* __restrict__ deg, int N, int* __restrict__ part) {
    __shared__ int red[256];
    int base = blockIdx.x * 1024, t = threadIdx.x;
    int s = 0;
#pragma unroll
    for (int j = 0; j < 4; ++j) {
        int i = base + j * 256 + t;
        if (i < N) s += deg[i];
    }
    red[t] = s;
    __syncthreads();
    for (int o = 128; o > 0; o >>= 1) {
        if (t < o) red[t] += red[t + o];
        __syncthreads();
    }
    if (t == 0) part[blockIdx.x] = red[0];
}

__global__ void k_scanpart(const int* __restrict__ part, int G, int E,
                           int* __restrict__ partOffs, int* __restrict__ offs, int N) {
    __shared__ int buf[1024];
    int t = threadIdx.x;
    int v = (t < G) ? part[t] : 0;
    buf[t] = v;
    __syncthreads();
    for (int o = 1; o < 1024; o <<= 1) {
        int x = (t >= o) ? buf[t - o] : 0;
        __syncthreads();
        buf[t] += x;
        __syncthreads();
    }
    if (t < G) partOffs[t] = buf[t] - v;
    if (t == 0) offs[N] = E;
}

__global__ void k_offsets(const int* __restrict__ deg, int N,
                          const int* __restrict__ partOffs, int* __restrict__ offs) {
    __shared__ int buf[1024];
    int base = blockIdx.x * 1024, t = threadIdx.x;
    int v = (base + t < N) ? deg[base + t] : 0;
    buf[t] = v;
    __syncthreads();
    for (int o = 1; o < 1024; o <<= 1) {
        int x = (t >= o) ? buf[t - o] : 0;
        __syncthreads();
        buf[t] += x;
        __syncthreads();
    }
    if (base + t < N) offs[base + t] = partOffs[blockIdx.x] + buf[t] - v;
}

__global__ void k_logsum(const int* __restrict__ deg, int N, float* __restrict__ lsum) {
    __shared__ float red[256];
    int i = blockIdx.x * 256 + threadIdx.x;
    float v = 0.f;
    if (i < N) {
        float dc = fmaxf((float)deg[i], 1.f);
        v = logf(dc + 1.f);
    }
    red[threadIdx.x] = v;
    __syncthreads();
    for (int s = 128; s > 0; s >>= 1) {
        if (threadIdx.x < s) red[threadIdx.x] += red[threadIdx.x + s];
        __syncthreads();
    }
    if (threadIdx.x == 0) atomicAdd(lsum, red[0]);
}

__global__ void k_scalers(const int* __restrict__ deg, int N, const float* __restrict__ lsum,
                          float* __restrict__ amp, float* __restrict__ att) {
    int i = blockIdx.x * 256 + threadIdx.x;
    if (i >= N) return;
    float dc = fmaxf((float)deg[i], 1.f);
    float ld = logf(dc + 1.f);
    float avg = *lsum / (float)N;
    amp[i] = ld / avg;
    att[i] = avg / ld;
}

__global__ void k_scatter(const int* __restrict__ src, const int* __restrict__ dst, int E,
                          const int* __restrict__ offs, int* __restrict__ cursor,
                          int* __restrict__ srcSorted) {
    int e = blockIdx.x * 256 + threadIdx.x;
    if (e >= E) return;
    int d = dst[e];
    int pos = offs[d] + atomicAdd(&cursor[d], 1);
    srcSorted[pos] = src[e];
}

// pre_w combined [64k x 128c], transposed to [c][k], split hi/lo bf16
__global__ void k_prew(const float* __restrict__ pre_w, u16* __restrict__ WpT_hi,
                       u16* __restrict__ WpT_lo) {
    int c = blockIdx.x, l = blockIdx.y, k = threadIdx.x;  // k<64
    float v = pre_w[(size_t)l * 8192 + (size_t)(k + (c >= 64 ? 64 : 0)) * 64 + (c & 63)];
    u16 h = f2bf(v);
    size_t o = ((size_t)l * 128 + c) * 64 + k;
    WpT_hi[o] = h;
    WpT_lo[o] = f2bf(v - bf2f(h));
}

// folded post_w @ lin_w -> WT[l][j=192][k=320] hi/lo bf16 (transposed, n-major)
__global__ void k_fold(const float* __restrict__ post_w, const float* __restrict__ lin_w,
                       u16* __restrict__ WT_hi, u16* __restrict__ WT_lo) {
    int l = blockIdx.y, k = blockIdx.x, j = threadIdx.x;  // k<320, j<192
    int third = j >> 6, c = j & 63;
    float out = 0.f;
    int r = -1;
    if (k < 64) r = (third == 0) ? k : -1;
    else        r = 64 + third * 256 + (k - 64);
    if (r >= 0) {
        const float* pw = post_w + (size_t)(l * 832 + r) * 64;
        const float* lw = lin_w + (size_t)l * 64 * 64;
        float s = 0.f;
        for (int kk = 0; kk < 64; ++kk) s += pw[kk] * lw[kk * 64 + c];
        out = s;
    }
    u16 h = f2bf(out);
    size_t o = ((size_t)l * 192 + j) * 320 + k;
    WT_hi[o] = h;
    WT_lo[o] = f2bf(out - bf2f(h));
}

__global__ void k_foldb(const float* __restrict__ post_b, const float* __restrict__ lin_b,
                        const float* __restrict__ lin_w, float* __restrict__ bpp) {
    int l = blockIdx.x, c = threadIdx.x;
    const float* pb = post_b + l * 64;
    const float* lw = lin_w + (size_t)l * 64 * 64;
    float s = lin_b[l * 64 + c];
    for (int k = 0; k < 64; ++k) s += pb[k] * lw[k * 64 + c];
    bpp[l * 64 + c] = s;
}

// ---------------- per-layer kernels ----------------

// P[M,64](+bias) , Q[M,64] = h[M,64] @ [Wt | Ws] via split-bf16 MFMA
__global__ __launch_bounds__(256) void k_gemm1(const float* __restrict__ h,
                                               const u16* __restrict__ WpT_hi,
                                               const u16* __restrict__ WpT_lo,
                                               const float* __restrict__ pre_b,
                                               float* __restrict__ P, float* __restrict__ Q,
                                               int M) {
    __shared__ u16 Ah[64 * 72], Al[64 * 72];    // [row][k 0:64], pitch 72
    __shared__ u16 Bh[128 * 72], Bl[128 * 72];  // [col][k 0:64], pitch 72
    int t = threadIdx.x, wid = t >> 6, lane = t & 63;
    int rows0 = blockIdx.x * 64;
    int quad = lane >> 4, l16 = lane & 15;
    int wm = wid & 1, wn = wid >> 1;

#pragma unroll
    for (int it = 0; it < 2; ++it) {
        int task = it * 256 + t;
        int r = task >> 3, seg = task & 7;
        int row = rows0 + r;
        float4 v0 = make_float4(0.f, 0.f, 0.f, 0.f), v1 = v0;
        if (row < M) {
            v0 = *(const float4*)&h[(size_t)row * 64 + seg * 8];
            v1 = *(const float4*)&h[(size_t)row * 64 + seg * 8 + 4];
        }
        s16x8 hv, lv;
        split8(v0, v1, hv, lv);
        *(s16x8*)&Ah[r * 72 + seg * 8] = hv;
        *(s16x8*)&Al[r * 72 + seg * 8] = lv;
    }
#pragma unroll
    for (int it = 0; it < 4; ++it) {
        int task = it * 256 + t;
        int c = task >> 3, seg = task & 7;
        *(s16x8*)&Bh[c * 72 + seg * 8] = *(const s16x8*)&WpT_hi[(size_t)c * 64 + seg * 8];
        *(s16x8*)&Bl[c * 72 + seg * 8] = *(const s16x8*)&WpT_lo[(size_t)c * 64 + seg * 8];
    }
    __syncthreads();

    f32x4 acc[2][4];
#pragma unroll
    for (int mt = 0; mt < 2; ++mt)
#pragma unroll
        for (int tt = 0; tt < 4; ++tt) acc[mt][tt] = (f32x4){0.f, 0.f, 0.f, 0.f};

#pragma unroll
    for (int c = 0; c < 2; ++c) {
        s16x8 ah[2], al[2];
#pragma unroll
        for (int mt = 0; mt < 2; ++mt) {
            int r = wm * 32 + mt * 16 + l16;
            ah[mt] = *(s16x8*)&Ah[r * 72 + c * 32 + quad * 8];
            al[mt] = *(s16x8*)&Al[r * 72 + c * 32 + quad * 8];
        }
#pragma unroll
        for (int tt = 0; tt < 4; ++tt) {
            int cc = wn * 64 + tt * 16 + l16;
            s16x8 bh = *(s16x8*)&Bh[cc * 72 + c * 32 + quad * 8];
            s16x8 bl = *(s16x8*)&Bl[cc * 72 + c * 32 + quad * 8];
#pragma unroll
            for (int mt = 0; mt < 2; ++mt) {
                acc[mt][tt] = MFMA(ah[mt], bh, acc[mt][tt]);
                acc[mt][tt] = MFMA(al[mt], bh, acc[mt][tt]);
                acc[mt][tt] = MFMA(ah[mt], bl, acc[mt][tt]);
            }
        }
    }

#pragma unroll
    for (int mt = 0; mt < 2; ++mt)
#pragma unroll
        for (int tt = 0; tt < 4; ++tt) {
            int col = wn * 64 + tt * 16 + l16;
#pragma unroll
            for (int r = 0; r < 4; ++r) {
                int row = rows0 + wm * 32 + mt * 16 + quad * 4 + r;
                if (row >= M) continue;
                float v = acc[mt][tt][r];
                if (col < 64) P[(size_t)row * 64 + col] = v + pre_b[col];
                else          Q[(size_t)row * 64 + col - 64] = v;
            }
        }
}

// one wave per node; lane = feature
__global__ __launch_bounds__(256) void k_agg(const float* __restrict__ P,
                                             const float* __restrict__ Q,
                                             const int* __restrict__ offs,
                                             const int* __restrict__ ss,
                                             float* __restrict__ AGG, int N) {
    int idx = blockIdx.x * 4 + (threadIdx.x >> 6);
    int lane = threadIdx.x & 63;
    if (idx >= N) return;
    int beg = offs[idx], end = offs[idx + 1];
    float p = P[(size_t)idx * 64 + lane];
    float sum = 0.f, sq = 0.f, mx = -3.4e38f, mn = 3.4e38f;
    int e = beg;
    for (; e + 4 <= end; e += 4) {
        int s0 = ss[e], s1 = ss[e + 1], s2 = ss[e + 2], s3 = ss[e + 3];
        float q0 = Q[(size_t)s0 * 64 + lane];
        float q1 = Q[(size_t)s1 * 64 + lane];
        float q2 = Q[(size_t)s2 * 64 + lane];
        float q3 = Q[(size_t)s3 * 64 + lane];
        float m0 = p + q0, m1 = p + q1, m2 = p + q2, m3 = p + q3;
        sum += m0; sq = fmaf(m0, m0, sq); mx = fmaxf(mx, m0); mn = fminf(mn, m0);
        sum += m1; sq = fmaf(m1, m1, sq); mx = fmaxf(mx, m1); mn = fminf(mn, m1);
        sum += m2; sq = fmaf(m2, m2, sq); mx = fmaxf(mx, m2); mn = fminf(mn, m2);
        sum += m3; sq = fmaf(m3, m3, sq); mx = fmaxf(mx, m3); mn = fminf(mn, m3);
    }
    for (; e < end; ++e) {
        int s = ss[e];
        float m = p + Q[(size_t)s * 64 + lane];
        sum += m; sq = fmaf(m, m, sq); mx = fmaxf(mx, m); mn = fminf(mn, m);
    }
    int deg = end - beg;
    float dc = fmaxf((float)deg, 1.f);
    float mean = sum / dc;
    float var = fmaxf(sq / dc - mean * mean, 0.f);
    float sd = sqrtf(var + EPSV);
    if (deg == 0) { mx = 0.f; mn = 0.f; }
    size_t o = (size_t)idx * 256;
    AGG[o + lane] = mean;
    AGG[o + 64 + lane] = mx;
    AGG[o + 128 + lane] = mn;
    AGG[o + 192 + lane] = sd;
}

// hOut = hIn + [hIn|AGG] @ WT (192 cols = 3 thirds) combined with amp/att + bpp
// K-loop split into two statically-bounded phases so acc[][] indexing is
// compile-time (dynamic indexing spilled acc to scratch in round 2:
// VGPR=52, WRITE_SIZE=366MB).
__global__ __launch_bounds__(256) void k_gemm2(const float* __restrict__ hIn,
                                               const float* __restrict__ AGG,
                                               const u16* __restrict__ WT_hi,
                                               const u16* __restrict__ WT_lo,
                                               const float* __restrict__ bpp,
                                               const float* __restrict__ amp,
                                               const float* __restrict__ att,
                                               float* __restrict__ hOut, int M) {
    __shared__ u16 Ah[64 * 40], Al[64 * 40];    // [row][k-chunk 32], pitch 40
    __shared__ u16 Bh[192 * 40], Bl[192 * 40];  // [col][k-chunk 32], pitch 40
    int t = threadIdx.x, wid = t >> 6, lane = t & 63;
    int rows0 = blockIdx.x * 64;
    int quad = lane >> 4, l16 = lane & 15;
    int wm = wid & 1, wn = wid >> 1;

    f32x4 acc[2][6];  // [mt][cg + third*2]
#pragma unroll
    for (int mt = 0; mt < 2; ++mt)
#pragma unroll
        for (int tt = 0; tt < 6; ++tt) acc[mt][tt] = (f32x4){0.f, 0.f, 0.f, 0.f};

    // ---- Phase 1: k 0..63 over hIn, only cols 0:64 (third 0) ----
#pragma unroll
    for (int chunk = 0; chunk < 2; ++chunk) {
        {
            int r = t >> 2, seg = t & 3;
            int row = rows0 + r;
            float4 v0 = make_float4(0.f, 0.f, 0.f, 0.f), v1 = v0;
            if (row < M) {
                v0 = *(const float4*)&hIn[(size_t)row * 64 + chunk * 32 + seg * 8];
                v1 = *(const float4*)&hIn[(size_t)row * 64 + chunk * 32 + seg * 8 + 4];
            }
            s16x8 hv, lv;
            split8(v0, v1, hv, lv);
            *(s16x8*)&Ah[r * 40 + seg * 8] = hv;
            *(s16x8*)&Al[r * 40 + seg * 8] = lv;
        }
        {
            int c = t >> 2, seg = t & 3;  // 64 cols x 4 segs = 256 tasks
            int k0g = chunk * 32;
            *(s16x8*)&Bh[c * 40 + seg * 8] = *(const s16x8*)&WT_hi[(size_t)c * 320 + k0g + seg * 8];
            *(s16x8*)&Bl[c * 40 + seg * 8] = *(const s16x8*)&WT_lo[(size_t)c * 320 + k0g + seg * 8];
        }
        __syncthreads();

        s16x8 ah[2], al[2];
#pragma unroll
        for (int mt = 0; mt < 2; ++mt) {
            int r = wm * 32 + mt * 16 + l16;
            ah[mt] = *(s16x8*)&Ah[r * 40 + quad * 8];
            al[mt] = *(s16x8*)&Al[r * 40 + quad * 8];
        }
#pragma unroll
        for (int tt = 0; tt < 2; ++tt) {
            int cc = wn * 32 + tt * 16 + l16;
            s16x8 bh = *(s16x8*)&Bh[cc * 40 + quad * 8];
            s16x8 bl = *(s16x8*)&Bl[cc * 40 + quad * 8];
#pragma unroll
            for (int mt = 0; mt < 2; ++mt) {
                acc[mt][tt] = MFMA(ah[mt], bh, acc[mt][tt]);
                acc[mt][tt] = MFMA(al[mt], bh, acc[mt][tt]);
                acc[mt][tt] = MFMA(ah[mt], bl, acc[mt][tt]);
            }
        }
        __syncthreads();
    }

    // ---- Phase 2: k 64..319 over AGG, all 192 cols ----
    for (int chunk = 0; chunk < 8; ++chunk) {
        {
            int r = t >> 2, seg = t & 3;
            int row = rows0 + r;
            float4 v0 = make_float4(0.f, 0.f, 0.f, 0.f), v1 = v0;
            if (row < M) {
                v0 = *(const float4*)&AGG[(size_t)row * 256 + chunk * 32 + seg * 8];
                v1 = *(const float4*)&AGG[(size_t)row * 256 + chunk * 32 + seg * 8 + 4];
            }
            s16x8 hv, lv;
            split8(v0, v1, hv, lv);
            *(s16x8*)&Ah[r * 40 + seg * 8] = hv;
            *(s16x8*)&Al[r * 40 + seg * 8] = lv;
        }
        {
            int k0g = 64 + chunk * 32;
#pragma unroll
            for (int it = 0; it < 3; ++it) {
                int task = it * 256 + t;  // 192 cols x 4 segs = 768 tasks
                int c = task >> 2, seg = task & 3;
                *(s16x8*)&Bh[c * 40 + seg * 8] = *(const s16x8*)&WT_hi[(size_t)c * 320 + k0g + seg * 8];
                *(s16x8*)&Bl[c * 40 + seg * 8] = *(const s16x8*)&WT_lo[(size_t)c * 320 + k0g + seg * 8];
            }
        }
        __syncthreads();

        s16x8 ah[2], al[2];
#pragma unroll
        for (int mt = 0; mt < 2; ++mt) {
            int r = wm * 32 + mt * 16 + l16;
            ah[mt] = *(s16x8*)&Ah[r * 40 + quad * 8];
            al[mt] = *(s16x8*)&Al[r * 40 + quad * 8];
        }
#pragma unroll
        for (int tt = 0; tt < 6; ++tt) {
            int cc = wn * 32 + (tt & 1) * 16 + (tt >> 1) * 64 + l16;
            s16x8 bh = *(s16x8*)&Bh[cc * 40 + quad * 8];
            s16x8 bl = *(s16x8*)&Bl[cc * 40 + quad * 8];
#pragma unroll
            for (int mt = 0; mt < 2; ++mt) {
                acc[mt][tt] = MFMA(ah[mt], bh, acc[mt][tt]);
                acc[mt][tt] = MFMA(al[mt], bh, acc[mt][tt]);
                acc[mt][tt] = MFMA(ah[mt], bl, acc[mt][tt]);
            }
        }
        __syncthreads();
    }

    // epilogue: combine thirds with amp/att, residual + folded bias
#pragma unroll
    for (int mt = 0; mt < 2; ++mt)
#pragma unroll
        for (int cg = 0; cg < 2; ++cg) {
            int col = wn * 32 + cg * 16 + l16;
            float bb = bpp[col];
#pragma unroll
            for (int r = 0; r < 4; ++r) {
                int row = rows0 + wm * 32 + mt * 16 + quad * 4 + r;
                if (row >= M) continue;
                float am = amp[row], at = att[row];
                float v = acc[mt][cg][r] + am * acc[mt][cg + 2][r] + at * acc[mt][cg + 4][r]
                        + hIn[(size_t)row * 64 + col] + bb;
                hOut[(size_t)row * 64 + col] = v;
            }
        }
}

// ---------------- launch ----------------

extern "C" void kernel_launch(void* const* d_in, const int* in_sizes, int n_in,
                              void* d_out, int out_size, void* d_ws, size_t ws_size,
                              hipStream_t stream) {
    const float* x      = (const float*)d_in[0];
    const int*   ei     = (const int*)d_in[1];
    const float* pre_w  = (const float*)d_in[2];
    const float* pre_b  = (const float*)d_in[3];
    const float* post_w = (const float*)d_in[4];
    const float* post_b = (const float*)d_in[5];
    const float* lin_w  = (const float*)d_in[6];
    const float* lin_b  = (const float*)d_in[7];

    const int N = in_sizes[0] / 64;
    const int E = in_sizes[1] / 2;
    const int L = in_sizes[2] / (128 * 64);

    const int* srcIdx = ei;
    const int* dstIdx = ei + E;

    char* ws = (char*)d_ws;
    size_t off = 0;
    auto alloc = [&](size_t bytes) {
        void* p = ws + off;
        off += (bytes + 255) & ~(size_t)255;
        return p;
    };
    int*   deg       = (int*)alloc((size_t)N * 4);
    int*   offs      = (int*)alloc((size_t)(N + 1) * 4);
    int*   cursor    = (int*)alloc((size_t)N * 4);
    int*   srcSorted = (int*)alloc((size_t)E * 4);
    int*   part      = (int*)alloc(1024 * 4);
    int*   partOffs  = (int*)alloc(1024 * 4);
    float* amp       = (float*)alloc((size_t)N * 4);
    float* att       = (float*)alloc((size_t)N * 4);
    float* lsum      = (float*)alloc(256);
    u16*   WpT_hi    = (u16*)alloc((size_t)L * 128 * 64 * 2);
    u16*   WpT_lo    = (u16*)alloc((size_t)L * 128 * 64 * 2);
    u16*   WT_hi     = (u16*)alloc((size_t)L * 192 * 320 * 2);
    u16*   WT_lo     = (u16*)alloc((size_t)L * 192 * 320 * 2);
    float* bpp       = (float*)alloc((size_t)L * 64 * 4);
    float* P         = (float*)alloc((size_t)N * 64 * 4);
    float* Q         = (float*)alloc((size_t)N * 64 * 4);
    float* AGG       = (float*)alloc((size_t)N * 256 * 4);
    float* hA        = (float*)alloc((size_t)N * 64 * 4);
    float* hB        = (float*)alloc((size_t)N * 64 * 4);
    (void)ws_size;

    hipMemsetAsync(deg, 0, (size_t)N * 4, stream);
    hipMemsetAsync(cursor, 0, (size_t)N * 4, stream);
    hipMemsetAsync(lsum, 0, 4, stream);

    int G1 = (N + 1023) / 1024;
    k_deg<<<(E + 255) / 256, 256, 0, stream>>>(dstIdx, E, deg);
    k_part<<<G1, 256, 0, stream>>>(deg, N, part);
    k_scanpart<<<1, 1024, 0, stream>>>(part, G1, E, partOffs, offs, N);
    k_offsets<<<G1, 1024, 0, stream>>>(deg, N, partOffs, offs);
    k_logsum<<<(N + 255) / 256, 256, 0, stream>>>(deg, N, lsum);
    k_scalers<<<(N + 255) / 256, 256, 0, stream>>>(deg, N, lsum, amp, att);
    k_scatter<<<(E + 255) / 256, 256, 0, stream>>>(srcIdx, dstIdx, E, offs, cursor, srcSorted);
    k_prew<<<dim3(128, L), 64, 0, stream>>>(pre_w, WpT_hi, WpT_lo);
    k_fold<<<dim3(320, L), 192, 0, stream>>>(post_w, lin_w, WT_hi, WT_lo);
    k_foldb<<<L, 64, 0, stream>>>(post_b, lin_b, lin_w, bpp);

    const float* hIn = x;
    float* hbuf[2] = {hA, hB};
    int gblk = (N + 63) / 64;
    for (int l = 0; l < L; ++l) {
        float* hOut = (l == L - 1) ? (float*)d_out : hbuf[l & 1];
        k_gemm1<<<gblk, 256, 0, stream>>>(hIn, WpT_hi + (size_t)l * 128 * 64,
                                          WpT_lo + (size_t)l * 128 * 64,
                                          pre_b + (size_t)l * 64, P, Q, N);
        k_agg<<<(N + 3) / 4, 256, 0, stream>>>(P, Q, offs, srcSorted, AGG, N);
        k_gemm2<<<gblk, 256, 0, stream>>>(hIn, AGG,
                                          WT_hi + (size_t)l * 192 * 320,
                                          WT_lo + (size_t)l * 192 * 320,
                                          bpp + (size_t)l * 64,
                                          amp, att, hOut, N);
        hIn = hOut;
    }
}

// Round 4
// 396.152 us; speedup vs baseline: 2.0967x; 1.1260x over previous
//
#include <hip/hip_runtime.h>
#include <math.h>

#define EPSV 1e-5f
#define EPB 8192   // edges per pass-1 block
#define NBP 128    // max buckets (N <= 65536 @ width 512)
#define CAP 12288  // pass-2 LDS edge capacity per bucket

typedef short s16x8 __attribute__((ext_vector_type(8)));
typedef float f32x4 __attribute__((ext_vector_type(4)));
typedef unsigned short u16;

#define MFMA(a, b, c) __builtin_amdgcn_mfma_f32_16x16x32_bf16(a, b, c, 0, 0, 0)

__device__ inline u16 f2bf(float f) {
    unsigned u = __float_as_uint(f);
    return (u16)((u + 0x7FFF + ((u >> 16) & 1)) >> 16);
}
__device__ inline float bf2f(u16 h) { return __uint_as_float(((unsigned)h) << 16); }

__device__ inline void split8(const float4& a, const float4& b, s16x8& hv, s16x8& lv) {
    float f[8] = {a.x, a.y, a.z, a.w, b.x, b.y, b.z, b.w};
#pragma unroll
    for (int i = 0; i < 8; ++i) {
        u16 h = f2bf(f[i]);
        hv[i] = (short)h;
        lv[i] = (short)f2bf(f[i] - bf2f(h));
    }
}

// ---------------- setup kernels ----------------

__global__ void k_init(int* __restrict__ deg, int* __restrict__ bucketCursor,
                       float* __restrict__ lsum, int N) {
    int i = blockIdx.x * 256 + threadIdx.x;
    if (i < N) deg[i] = 0;
    if (i < NBP) bucketCursor[i] = 0;
    if (i == 0) *lsum = 0.f;
}

__global__ void k_deg(const int* __restrict__ dst, int E, int* __restrict__ deg) {
    int e = blockIdx.x * 256 + threadIdx.x;
    if (e < E) atomicAdd(&deg[dst[e]], 1);
}

// partial sums per 1024 nodes + global log-degree sum (fused)
__global__ void k_part(const int* __restrict__ deg, int N, int* __restrict__ part,
                       float* __restrict__ lsum) {
    __shared__ int red[256];
    __shared__ float redf[256];
    int base = blockIdx.x * 1024, t = threadIdx.x;
    int s = 0;
    float ls = 0.f;
#pragma unroll
    for (int j = 0; j < 4; ++j) {
        int i = base + j * 256 + t;
        if (i < N) {
            int d = deg[i];
            s += d;
            ls += logf(fmaxf((float)d, 1.f) + 1.f);
        }
    }
    red[t] = s;
    redf[t] = ls;
    __syncthreads();
    for (int o = 128; o > 0; o >>= 1) {
        if (t < o) { red[t] += red[t + o]; redf[t] += redf[t + o]; }
        __syncthreads();
    }
    if (t == 0) {
        part[blockIdx.x] = red[0];
        atomicAdd(lsum, redf[0]);
    }
}

__global__ void k_scanpart(const int* __restrict__ part, int G, int E,
                           int* __restrict__ partOffs, int* __restrict__ offs, int N) {
    __shared__ int buf[1024];
    int t = threadIdx.x;
    int v = (t < G) ? part[t] : 0;
    buf[t] = v;
    __syncthreads();
    for (int o = 1; o < 1024; o <<= 1) {
        int x = (t >= o) ? buf[t - o] : 0;
        __syncthreads();
        buf[t] += x;
        __syncthreads();
    }
    if (t < G) partOffs[t] = buf[t] - v;
    if (t == 0) offs[N] = E;
}

// per-node offsets + amp/att scalers (fused)
__global__ void k_offsets(const int* __restrict__ deg, int N,
                          const int* __restrict__ partOffs, const float* __restrict__ lsum,
                          int* __restrict__ offs, float* __restrict__ amp,
                          float* __restrict__ att) {
    __shared__ int buf[1024];
    int base = blockIdx.x * 1024, t = threadIdx.x;
    int v = (base + t < N) ? deg[base + t] : 0;
    buf[t] = v;
    __syncthreads();
    for (int o = 1; o < 1024; o <<= 1) {
        int x = (t >= o) ? buf[t - o] : 0;
        __syncthreads();
        buf[t] += x;
        __syncthreads();
    }
    if (base + t < N) {
        offs[base + t] = partOffs[blockIdx.x] + buf[t] - v;
        float dc = fmaxf((float)v, 1.f);
        float ld = logf(dc + 1.f);
        float avg = *lsum / (float)N;
        amp[base + t] = ld / avg;
        att[base + t] = avg / ld;
    }
}

// pass 1: partition edges into 512-node buckets with coalesced run writes
__global__ __launch_bounds__(512) void k_bucket(const int* __restrict__ src,
                                                const int* __restrict__ dst, int E,
                                                const int* __restrict__ offs,
                                                int* __restrict__ bucketCursor,
                                                int2* __restrict__ edgeTmp) {
    __shared__ int cnt[NBP], loff[NBP], lpos[NBP], gbase[NBP], bstart[NBP];
    __shared__ int2 stage[EPB];
    int t = threadIdx.x;
    int base = blockIdx.x * EPB;
    int cntE = min(EPB, E - base);
    for (int i = t; i < NBP; i += 512) cnt[i] = 0;
    __syncthreads();
    int2 ed[16];
#pragma unroll
    for (int j = 0; j < 16; ++j) {
        int idx = j * 512 + t;
        if (idx < cntE) {
            int e = base + idx;
            ed[j].x = src[e];
            ed[j].y = dst[e];
            atomicAdd(&cnt[((unsigned)ed[j].y) >> 9], 1);
        } else ed[j].y = -1;
    }
    __syncthreads();
    if (t == 0) {
        int run = 0;
        for (int i = 0; i < NBP; ++i) { loff[i] = run; run += cnt[i]; }
    }
    __syncthreads();
    if (t < NBP) {
        lpos[t] = loff[t];
        if (cnt[t] > 0) {
            gbase[t] = atomicAdd(&bucketCursor[t], cnt[t]);
            bstart[t] = offs[t << 9];
        }
    }
    __syncthreads();
#pragma unroll
    for (int j = 0; j < 16; ++j) {
        if (ed[j].y >= 0) {
            int b = ((unsigned)ed[j].y) >> 9;
            int p = atomicAdd(&lpos[b], 1);
            stage[p] = ed[j];
        }
    }
    __syncthreads();
    for (int i = t; i < cntE; i += 512) {
        int2 pr = stage[i];
        int b = ((unsigned)pr.y) >> 9;
        edgeTmp[(size_t)bstart[b] + gbase[b] + (i - loff[b])] = pr;
    }
}

// pass 2: counting-sort each bucket in LDS, write srcSorted coalesced
__global__ __launch_bounds__(1024) void k_csort(const int2* __restrict__ edgeTmp,
                                                const int* __restrict__ offs,
                                                int* __restrict__ srcSorted, int N) {
    __shared__ int loffs[513];
    __shared__ int lcur[512];
    __shared__ int stageSrc[CAP];
    int b = blockIdx.x, t = threadIdx.x;
    int n0 = b << 9;
    int nodes = min(512, N - n0);
    if (t <= nodes) loffs[t] = offs[n0 + t];
    if (t < 512) lcur[t] = 0;
    __syncthreads();
    int e0 = loffs[0], e1 = loffs[nodes];
    int cnt = e1 - e0;
    if (cnt <= CAP) {
        for (int i = t; i < cnt; i += 1024) {
            int2 p = edgeTmp[e0 + i];
            int dl = p.y - n0;
            int r = atomicAdd(&lcur[dl], 1);
            stageSrc[loffs[dl] - e0 + r] = p.x;
        }
        __syncthreads();
        for (int i = t; i < cnt; i += 1024) srcSorted[e0 + i] = stageSrc[i];
    } else {
        for (int i = t; i < cnt; i += 1024) {
            int2 p = edgeTmp[e0 + i];
            int dl = p.y - n0;
            int r = atomicAdd(&lcur[dl], 1);
            srcSorted[loffs[dl] + r] = p.x;
        }
    }
}

// merged weight prep: bx<320 fold WT, bx<448 prew, bx==448 foldb
__global__ void k_wprep(const float* __restrict__ pre_w, const float* __restrict__ post_w,
                        const float* __restrict__ post_b, const float* __restrict__ lin_w,
                        const float* __restrict__ lin_b, u16* __restrict__ WpT_hi,
                        u16* __restrict__ WpT_lo, u16* __restrict__ WT_hi,
                        u16* __restrict__ WT_lo, float* __restrict__ bpp) {
    int l = blockIdx.y, bx = blockIdx.x, t = threadIdx.x;
    if (bx < 320) {
        int k = bx, j = t;  // j<192
        int third = j >> 6, c = j & 63;
        float out = 0.f;
        int r = -1;
        if (k < 64) r = (third == 0) ? k : -1;
        else        r = 64 + third * 256 + (k - 64);
        if (r >= 0) {
            const float* pw = post_w + (size_t)(l * 832 + r) * 64;
            const float* lw = lin_w + (size_t)l * 64 * 64;
            float s = 0.f;
            for (int kk = 0; kk < 64; ++kk) s += pw[kk] * lw[kk * 64 + c];
            out = s;
        }
        u16 h = f2bf(out);
        size_t o = ((size_t)l * 192 + j) * 320 + k;
        WT_hi[o] = h;
        WT_lo[o] = f2bf(out - bf2f(h));
    } else if (bx < 448) {
        if (t < 64) {
            int c = bx - 320, k = t;
            float v = pre_w[(size_t)l * 8192 + (size_t)(k + (c >= 64 ? 64 : 0)) * 64 + (c & 63)];
            u16 h = f2bf(v);
            size_t o = ((size_t)l * 128 + c) * 64 + k;
            WpT_hi[o] = h;
            WpT_lo[o] = f2bf(v - bf2f(h));
        }
    } else {
        if (t < 64) {
            int c = t;
            const float* pb = post_b + l * 64;
            const float* lw = lin_w + (size_t)l * 64 * 64;
            float s = lin_b[l * 64 + c];
            for (int k = 0; k < 64; ++k) s += pb[k] * lw[k * 64 + c];
            bpp[l * 64 + c] = s;
        }
    }
}

// ---------------- per-layer kernels ----------------

// P[M,64] fp32 (+bias), Qh[M,64] bf16 = h[M,64] @ [Wt | Ws] via split-bf16 MFMA
__global__ __launch_bounds__(256) void k_gemm1(const float* __restrict__ h,
                                               const u16* __restrict__ WpT_hi,
                                               const u16* __restrict__ WpT_lo,
                                               const float* __restrict__ pre_b,
                                               float* __restrict__ P, u16* __restrict__ Qh,
                                               int M) {
    __shared__ u16 Ah[64 * 72], Al[64 * 72];    // [row][k 0:64], pitch 72
    __shared__ u16 Bh[128 * 72], Bl[128 * 72];  // [col][k 0:64], pitch 72
    int t = threadIdx.x, wid = t >> 6, lane = t & 63;
    int rows0 = blockIdx.x * 64;
    int quad = lane >> 4, l16 = lane & 15;
    int wm = wid & 1, wn = wid >> 1;

#pragma unroll
    for (int it = 0; it < 2; ++it) {
        int task = it * 256 + t;
        int r = task >> 3, seg = task & 7;
        int row = rows0 + r;
        float4 v0 = make_float4(0.f, 0.f, 0.f, 0.f), v1 = v0;
        if (row < M) {
            v0 = *(const float4*)&h[(size_t)row * 64 + seg * 8];
            v1 = *(const float4*)&h[(size_t)row * 64 + seg * 8 + 4];
        }
        s16x8 hv, lv;
        split8(v0, v1, hv, lv);
        *(s16x8*)&Ah[r * 72 + seg * 8] = hv;
        *(s16x8*)&Al[r * 72 + seg * 8] = lv;
    }
#pragma unroll
    for (int it = 0; it < 4; ++it) {
        int task = it * 256 + t;
        int c = task >> 3, seg = task & 7;
        *(s16x8*)&Bh[c * 72 + seg * 8] = *(const s16x8*)&WpT_hi[(size_t)c * 64 + seg * 8];
        *(s16x8*)&Bl[c * 72 + seg * 8] = *(const s16x8*)&WpT_lo[(size_t)c * 64 + seg * 8];
    }
    __syncthreads();

    f32x4 acc[2][4];
#pragma unroll
    for (int mt = 0; mt < 2; ++mt)
#pragma unroll
        for (int tt = 0; tt < 4; ++tt) acc[mt][tt] = (f32x4){0.f, 0.f, 0.f, 0.f};

#pragma unroll
    for (int c = 0; c < 2; ++c) {
        s16x8 ah[2], al[2];
#pragma unroll
        for (int mt = 0; mt < 2; ++mt) {
            int r = wm * 32 + mt * 16 + l16;
            ah[mt] = *(s16x8*)&Ah[r * 72 + c * 32 + quad * 8];
            al[mt] = *(s16x8*)&Al[r * 72 + c * 32 + quad * 8];
        }
#pragma unroll
        for (int tt = 0; tt < 4; ++tt) {
            int cc = wn * 64 + tt * 16 + l16;
            s16x8 bh = *(s16x8*)&Bh[cc * 72 + c * 32 + quad * 8];
            s16x8 bl = *(s16x8*)&Bl[cc * 72 + c * 32 + quad * 8];
#pragma unroll
            for (int mt = 0; mt < 2; ++mt) {
                acc[mt][tt] = MFMA(ah[mt], bh, acc[mt][tt]);
                acc[mt][tt] = MFMA(al[mt], bh, acc[mt][tt]);
                acc[mt][tt] = MFMA(ah[mt], bl, acc[mt][tt]);
            }
        }
    }

#pragma unroll
    for (int mt = 0; mt < 2; ++mt)
#pragma unroll
        for (int tt = 0; tt < 4; ++tt) {
            int col = wn * 64 + tt * 16 + l16;
#pragma unroll
            for (int r = 0; r < 4; ++r) {
                int row = rows0 + wm * 32 + mt * 16 + quad * 4 + r;
                if (row >= M) continue;
                float v = acc[mt][tt][r];
                if (col < 64) P[(size_t)row * 64 + col] = v + pre_b[col];
                else          Qh[(size_t)row * 64 + (col - 64)] = f2bf(v);
            }
        }
}

// one wave per node; lane = feature; Q gathered as bf16, AGG written bf16
__global__ __launch_bounds__(256) void k_agg(const float* __restrict__ P,
                                             const u16* __restrict__ Qh,
                                             const int* __restrict__ offs,
                                             const int* __restrict__ ss,
                                             u16* __restrict__ AGGh, int N) {
    int idx = blockIdx.x * 4 + (threadIdx.x >> 6);
    int lane = threadIdx.x & 63;
    if (idx >= N) return;
    int beg = offs[idx], end = offs[idx + 1];
    float p = P[(size_t)idx * 64 + lane];
    float sum = 0.f, sq = 0.f, mx = -3.4e38f, mn = 3.4e38f;
    int e = beg;
    for (; e + 4 <= end; e += 4) {
        int s0 = ss[e], s1 = ss[e + 1], s2 = ss[e + 2], s3 = ss[e + 3];
        float q0 = bf2f(Qh[(size_t)s0 * 64 + lane]);
        float q1 = bf2f(Qh[(size_t)s1 * 64 + lane]);
        float q2 = bf2f(Qh[(size_t)s2 * 64 + lane]);
        float q3 = bf2f(Qh[(size_t)s3 * 64 + lane]);
        float m0 = p + q0, m1 = p + q1, m2 = p + q2, m3 = p + q3;
        sum += m0; sq = fmaf(m0, m0, sq); mx = fmaxf(mx, m0); mn = fminf(mn, m0);
        sum += m1; sq = fmaf(m1, m1, sq); mx = fmaxf(mx, m1); mn = fminf(mn, m1);
        sum += m2; sq = fmaf(m2, m2, sq); mx = fmaxf(mx, m2); mn = fminf(mn, m2);
        sum += m3; sq = fmaf(m3, m3, sq); mx = fmaxf(mx, m3); mn = fminf(mn, m3);
    }
    for (; e < end; ++e) {
        int s = ss[e];
        float m = p + bf2f(Qh[(size_t)s * 64 + lane]);
        sum += m; sq = fmaf(m, m, sq); mx = fmaxf(mx, m); mn = fminf(mn, m);
    }
    int deg = end - beg;
    float dc = fmaxf((float)deg, 1.f);
    float mean = sum / dc;
    float var = fmaxf(sq / dc - mean * mean, 0.f);
    float sd = sqrtf(var + EPSV);
    if (deg == 0) { mx = 0.f; mn = 0.f; }
    size_t o = (size_t)idx * 256;
    AGGh[o + lane] = f2bf(mean);
    AGGh[o + 64 + lane] = f2bf(mx);
    AGGh[o + 128 + lane] = f2bf(mn);
    AGGh[o + 192 + lane] = f2bf(sd);
}

// hOut = hIn + [hIn|AGG] @ WT (192 cols = 3 thirds) combined with amp/att + bpp
// Phase 2 A is bf16 (AGGh direct, hi only): 2 MFMAs per tile.
__global__ __launch_bounds__(256) void k_gemm2(const float* __restrict__ hIn,
                                               const u16* __restrict__ AGGh,
                                               const u16* __restrict__ WT_hi,
                                               const u16* __restrict__ WT_lo,
                                               const float* __restrict__ bpp,
                                               const float* __restrict__ amp,
                                               const float* __restrict__ att,
                                               float* __restrict__ hOut, int M) {
    __shared__ u16 Ah[64 * 40], Al[64 * 40];    // [row][k-chunk 32], pitch 40
    __shared__ u16 Bh[192 * 40], Bl[192 * 40];  // [col][k-chunk 32], pitch 40
    int t = threadIdx.x, wid = t >> 6, lane = t & 63;
    int rows0 = blockIdx.x * 64;
    int quad = lane >> 4, l16 = lane & 15;
    int wm = wid & 1, wn = wid >> 1;

    f32x4 acc[2][6];  // [mt][cg + third*2]
#pragma unroll
    for (int mt = 0; mt < 2; ++mt)
#pragma unroll
        for (int tt = 0; tt < 6; ++tt) acc[mt][tt] = (f32x4){0.f, 0.f, 0.f, 0.f};

    // ---- Phase 1: k 0..63 over hIn (full hi/lo split), only cols 0:64 ----
#pragma unroll
    for (int chunk = 0; chunk < 2; ++chunk) {
        {
            int r = t >> 2, seg = t & 3;
            int row = rows0 + r;
            float4 v0 = make_float4(0.f, 0.f, 0.f, 0.f), v1 = v0;
            if (row < M) {
                v0 = *(const float4*)&hIn[(size_t)row * 64 + chunk * 32 + seg * 8];
                v1 = *(const float4*)&hIn[(size_t)row * 64 + chunk * 32 + seg * 8 + 4];
            }
            s16x8 hv, lv;
            split8(v0, v1, hv, lv);
            *(s16x8*)&Ah[r * 40 + seg * 8] = hv;
            *(s16x8*)&Al[r * 40 + seg * 8] = lv;
        }
        {
            int c = t >> 2, seg = t & 3;
            int k0g = chunk * 32;
            *(s16x8*)&Bh[c * 40 + seg * 8] = *(const s16x8*)&WT_hi[(size_t)c * 320 + k0g + seg * 8];
            *(s16x8*)&Bl[c * 40 + seg * 8] = *(const s16x8*)&WT_lo[(size_t)c * 320 + k0g + seg * 8];
        }
        __syncthreads();

        s16x8 ah[2], al[2];
#pragma unroll
        for (int mt = 0; mt < 2; ++mt) {
            int r = wm * 32 + mt * 16 + l16;
            ah[mt] = *(s16x8*)&Ah[r * 40 + quad * 8];
            al[mt] = *(s16x8*)&Al[r * 40 + quad * 8];
        }
#pragma unroll
        for (int tt = 0; tt < 2; ++tt) {
            int cc = wn * 32 + tt * 16 + l16;
            s16x8 bh = *(s16x8*)&Bh[cc * 40 + quad * 8];
            s16x8 bl = *(s16x8*)&Bl[cc * 40 + quad * 8];
#pragma unroll
            for (int mt = 0; mt < 2; ++mt) {
                acc[mt][tt] = MFMA(ah[mt], bh, acc[mt][tt]);
                acc[mt][tt] = MFMA(al[mt], bh, acc[mt][tt]);
                acc[mt][tt] = MFMA(ah[mt], bl, acc[mt][tt]);
            }
        }
        __syncthreads();
    }

    // ---- Phase 2: k 64..319 over AGGh (bf16, hi only), all 192 cols ----
    for (int chunk = 0; chunk < 8; ++chunk) {
        {
            int r = t >> 2, seg = t & 3;
            int row = rows0 + r;
            s16x8 v = (s16x8){0, 0, 0, 0, 0, 0, 0, 0};
            if (row < M) v = *(const s16x8*)&AGGh[(size_t)row * 256 + chunk * 32 + seg * 8];
            *(s16x8*)&Ah[r * 40 + seg * 8] = v;
        }
        {
            int k0g = 64 + chunk * 32;
#pragma unroll
            for (int it = 0; it < 3; ++it) {
                int task = it * 256 + t;  // 192 cols x 4 segs
                int c = task >> 2, seg = task & 3;
                *(s16x8*)&Bh[c * 40 + seg * 8] = *(const s16x8*)&WT_hi[(size_t)c * 320 + k0g + seg * 8];
                *(s16x8*)&Bl[c * 40 + seg * 8] = *(const s16x8*)&WT_lo[(size_t)c * 320 + k0g + seg * 8];
            }
        }
        __syncthreads();

        s16x8 ah[2];
#pragma unroll
        for (int mt = 0; mt < 2; ++mt) {
            int r = wm * 32 + mt * 16 + l16;
            ah[mt] = *(s16x8*)&Ah[r * 40 + quad * 8];
        }
#pragma unroll
        for (int tt = 0; tt < 6; ++tt) {
            int cc = wn * 32 + (tt & 1) * 16 + (tt >> 1) * 64 + l16;
            s16x8 bh = *(s16x8*)&Bh[cc * 40 + quad * 8];
            s16x8 bl = *(s16x8*)&Bl[cc * 40 + quad * 8];
#pragma unroll
            for (int mt = 0; mt < 2; ++mt) {
                acc[mt][tt] = MFMA(ah[mt], bh, acc[mt][tt]);
                acc[mt][tt] = MFMA(ah[mt], bl, acc[mt][tt]);
            }
        }
        __syncthreads();
    }

    // epilogue: combine thirds with amp/att, residual + folded bias
#pragma unroll
    for (int mt = 0; mt < 2; ++mt)
#pragma unroll
        for (int cg = 0; cg < 2; ++cg) {
            int col = wn * 32 + cg * 16 + l16;
            float bb = bpp[col];
#pragma unroll
            for (int r = 0; r < 4; ++r) {
                int row = rows0 + wm * 32 + mt * 16 + quad * 4 + r;
                if (row >= M) continue;
                float am = amp[row], at = att[row];
                float v = acc[mt][cg][r] + am * acc[mt][cg + 2][r] + at * acc[mt][cg + 4][r]
                        + hIn[(size_t)row * 64 + col] + bb;
                hOut[(size_t)row * 64 + col] = v;
            }
        }
}

// ---------------- launch ----------------

extern "C" void kernel_launch(void* const* d_in, const int* in_sizes, int n_in,
                              void* d_out, int out_size, void* d_ws, size_t ws_size,
                              hipStream_t stream) {
    const float* x      = (const float*)d_in[0];
    const int*   ei     = (const int*)d_in[1];
    const float* pre_w  = (const float*)d_in[2];
    const float* pre_b  = (const float*)d_in[3];
    const float* post_w = (const float*)d_in[4];
    const float* post_b = (const float*)d_in[5];
    const float* lin_w  = (const float*)d_in[6];
    const float* lin_b  = (const float*)d_in[7];

    const int N = in_sizes[0] / 64;
    const int E = in_sizes[1] / 2;
    const int L = in_sizes[2] / (128 * 64);

    const int* srcIdx = ei;
    const int* dstIdx = ei + E;

    char* ws = (char*)d_ws;
    size_t off = 0;
    auto alloc = [&](size_t bytes) {
        void* p = ws + off;
        off += (bytes + 255) & ~(size_t)255;
        return p;
    };
    int*   deg        = (int*)alloc((size_t)N * 4);
    int*   offs       = (int*)alloc((size_t)(N + 1) * 4);
    int*   srcSorted  = (int*)alloc((size_t)E * 4);
    int2*  edgeTmp    = (int2*)alloc((size_t)E * 8);
    int*   part       = (int*)alloc(1024 * 4);
    int*   partOffs   = (int*)alloc(1024 * 4);
    int*   bucketCur  = (int*)alloc(NBP * 4);
    float* amp        = (float*)alloc((size_t)N * 4);
    float* att        = (float*)alloc((size_t)N * 4);
    float* lsum       = (float*)alloc(256);
    u16*   WpT_hi     = (u16*)alloc((size_t)L * 128 * 64 * 2);
    u16*   WpT_lo     = (u16*)alloc((size_t)L * 128 * 64 * 2);
    u16*   WT_hi      = (u16*)alloc((size_t)L * 192 * 320 * 2);
    u16*   WT_lo      = (u16*)alloc((size_t)L * 192 * 320 * 2);
    float* bpp        = (float*)alloc((size_t)L * 64 * 4);
    float* P          = (float*)alloc((size_t)N * 64 * 4);
    u16*   Qh         = (u16*)alloc((size_t)N * 64 * 2);
    u16*   AGGh       = (u16*)alloc((size_t)N * 256 * 2);
    float* hA         = (float*)alloc((size_t)N * 64 * 4);
    float* hB         = (float*)alloc((size_t)N * 64 * 4);
    (void)ws_size;

    int G1 = (N + 1023) / 1024;
    int NB = (N + 511) >> 9;
    int NB1 = (E + EPB - 1) / EPB;

    k_init<<<(N + 255) / 256, 256, 0, stream>>>(deg, bucketCur, lsum, N);
    k_deg<<<(E + 255) / 256, 256, 0, stream>>>(dstIdx, E, deg);
    k_part<<<G1, 256, 0, stream>>>(deg, N, part, lsum);
    k_scanpart<<<1, 1024, 0, stream>>>(part, G1, E, partOffs, offs, N);
    k_offsets<<<G1, 1024, 0, stream>>>(deg, N, partOffs, lsum, offs, amp, att);
    k_bucket<<<NB1, 512, 0, stream>>>(srcIdx, dstIdx, E, offs, bucketCur, edgeTmp);
    k_csort<<<NB, 1024, 0, stream>>>(edgeTmp, offs, srcSorted, N);
    k_wprep<<<dim3(449, L), 192, 0, stream>>>(pre_w, post_w, post_b, lin_w, lin_b,
                                              WpT_hi, WpT_lo, WT_hi, WT_lo, bpp);

    const float* hIn = x;
    float* hbuf[2] = {hA, hB};
    int gblk = (N + 63) / 64;
    for (int l = 0; l < L; ++l) {
        float* hOut = (l == L - 1) ? (float*)d_out : hbuf[l & 1];
        k_gemm1<<<gblk, 256, 0, stream>>>(hIn, WpT_hi + (size_t)l * 128 * 64,
                                          WpT_lo + (size_t)l * 128 * 64,
                                          pre_b + (size_t)l * 64, P, Qh, N);
        k_agg<<<(N + 3) / 4, 256, 0, stream>>>(P, Qh, offs, srcSorted, AGGh, N);
        k_gemm2<<<gblk, 256, 0, stream>>>(hIn, AGGh,
                                          WT_hi + (size_t)l * 192 * 320,
                                          WT_lo + (size_t)l * 192 * 320,
                                          bpp + (size_t)l * 64,
                                          amp, att, hOut, N);
        hIn = hOut;
    }
}